// Round 11
// baseline (270.422 us; speedup 1.0000x reference)
//
#include <hip/hip_runtime.h>
#include <stdint.h>

typedef unsigned short u16;
typedef unsigned int   u32;
typedef __attribute__((ext_vector_type(8))) short bf16x8;
typedef __attribute__((ext_vector_type(4))) float f32x4;

__device__ __forceinline__ u16 f2bf(float f) {
    union { float f; u32 u; } v; v.f = f;
    return (u16)((v.u + 0x7FFFu + ((v.u >> 16) & 1u)) >> 16);  // RNE
}
__device__ __forceinline__ float bf2f(u16 h) {
    union { u32 u; float f; } v; v.u = ((u32)h) << 16; return v.f;
}
__device__ __forceinline__ u32 fbits(float f) {
    union { float f; u32 u; } v; v.f = f; return v.u;
}

__device__ __forceinline__ void async16(const u16* g, u16* l) {
    typedef __attribute__((address_space(1))) const u32 gq;
    typedef __attribute__((address_space(3))) u32 lq;
    __builtin_amdgcn_global_load_lds((gq*)g, (lq*)l, 16, 0, 0);
}

// ---------------------------------------------------------------------------
// Prep (fused): blocks 0..10239 concat+convert x rows; 10240.. weight tiles.
// ---------------------------------------------------------------------------
__global__ void cvt_all_k(const float* __restrict__ xo, const float* __restrict__ xc,
                          u16* __restrict__ Xc,
                          const float* __restrict__ Wq, const float* __restrict__ Wkv,
                          const float* __restrict__ Wp,
                          u16* __restrict__ Wqt, u16* __restrict__ Wkt,
                          u16* __restrict__ Wpt)
{
    __shared__ __align__(16) u16 Ts[64][72];
    int id = blockIdx.x, t = threadIdx.x;
    if (id < 10240) {
        int row = id, cid = t * 4;
        int b = row >= 5120, s = row - b * 5120;
        const float* src = (s < 1024)
            ? xo + ((size_t)(b * 1024 + s)) * 1024 + cid
            : xc + ((size_t)(b * 4096 + s - 1024)) * 1024 + cid;
        float4 f = *(const float4*)src;
        union { u16 a[4]; uint2 v; } p;
        p.a[0]=f2bf(f.x); p.a[1]=f2bf(f.y); p.a[2]=f2bf(f.z); p.a[3]=f2bf(f.w);
        *(uint2*)(Xc + (size_t)row * 1024 + cid) = p.v;
        return;
    }
    int wid = id - 10240;
    const float* W; u16* Wt; int N, tile;
    if (wid < 256)      { W = Wq;  Wt = Wqt; N = 1024; tile = wid; }
    else if (wid < 768) { W = Wkv; Wt = Wkt; N = 2048; tile = wid - 256; }
    else                { W = Wp;  Wt = Wpt; N = 1024; tile = wid - 768; }
    int nt = N >> 6;
    int n0 = (tile % nt) * 64, k0 = (tile / nt) * 64;
    int lr = t >> 2, lc = (t & 3) * 16;
    const float* src = W + (size_t)(k0 + lr) * N + n0 + lc;
    union { u16 a[8]; uint4 v; } p0, p1;
    float4 f0 = *(const float4*)(src),      f1 = *(const float4*)(src + 4);
    float4 f2 = *(const float4*)(src + 8),  f3 = *(const float4*)(src + 12);
    p0.a[0]=f2bf(f0.x); p0.a[1]=f2bf(f0.y); p0.a[2]=f2bf(f0.z); p0.a[3]=f2bf(f0.w);
    p0.a[4]=f2bf(f1.x); p0.a[5]=f2bf(f1.y); p0.a[6]=f2bf(f1.z); p0.a[7]=f2bf(f1.w);
    p1.a[0]=f2bf(f2.x); p1.a[1]=f2bf(f2.y); p1.a[2]=f2bf(f2.z); p1.a[3]=f2bf(f2.w);
    p1.a[4]=f2bf(f3.x); p1.a[5]=f2bf(f3.y); p1.a[6]=f2bf(f3.z); p1.a[7]=f2bf(f3.w);
    *(uint4*)&Ts[lr][lc]     = p0.v;
    *(uint4*)&Ts[lr][lc + 8] = p1.v;
    __syncthreads();
    union { u16 a[8]; uint4 v; } q0, q1;
#pragma unroll
    for (int j = 0; j < 8; ++j) q0.a[j] = Ts[lc + j][lr];
#pragma unroll
    for (int j = 0; j < 8; ++j) q1.a[j] = Ts[lc + 8 + j][lr];
    u16* dst = Wt + (size_t)(n0 + lr) * 1024 + k0 + lc;
    *(uint4*)dst       = q0.v;
    *(uint4*)(dst + 8) = q1.v;
}

// ---------------------------------------------------------------------------
// Fused Q+KV GEMM (1408 blocks of 128x128, BK=32, m97-style).
// ---------------------------------------------------------------------------
__global__ __launch_bounds__(256, 2)
void gemm_qkv(const u16* __restrict__ A, const u16* __restrict__ Wqt,
              const u16* __restrict__ Wkt, u16* __restrict__ q,
              u16* __restrict__ Kh, u16* __restrict__ Vh)
{
    __shared__ __align__(16) u16 smem[17408];   // main: As|Bs; V-epi: T[128][136]
    u16* As = smem;
    u16* Bs = smem + 4096;

    const int t = threadIdx.x, w = t >> 6;
    const int lane = t & 63, quad = lane >> 4, l16 = lane & 15;
    const int id = blockIdx.x;
    const bool qm = id >= 1280;
    int m0, n0; const u16* Bt;
    if (qm) { int t2 = id - 1280; m0 = (t2 >> 3) * 128; n0 = (t2 & 7) * 128; Bt = Wqt; }
    else    { m0 = (id >> 4) * 128; n0 = (id & 15) * 128; Bt = Wkt; }
    const int wr = (w >> 1) * 64, wc = (w & 1) * 64;

    const int sr0 = w * 32 + (lane >> 2), sr1 = sr0 + 16;
    const int cg  = (lane & 3) ^ ((lane >> 4) & 3);
    u16* abase = As + w * 1024;
    u16* bbase = Bs + w * 1024;

    const u16 *ar0, *ar1;
    {
        int g0 = m0 + sr0, g1 = m0 + sr1;
        if (qm) {
            ar0 = A + ((size_t)(g0 >> 10) * 5120 + (g0 & 1023)) * 1024;
            ar1 = A + ((size_t)(g1 >> 10) * 5120 + (g1 & 1023)) * 1024;
        } else {
            ar0 = A + (size_t)g0 * 1024;
            ar1 = A + (size_t)g1 * 1024;
        }
        ar0 += cg * 8; ar1 += cg * 8;
    }
    const u16* br0 = Bt + (size_t)(n0 + sr0) * 1024 + cg * 8;
    const u16* br1 = Bt + (size_t)(n0 + sr1) * 1024 + cg * 8;

    f32x4 acc[4][4] = {};
    const int sel = (quad ^ (l16 >> 2)) * 8;

    for (int k0 = 0; k0 < 1024; k0 += 32) {
        async16(ar0 + k0, abase);
        async16(ar1 + k0, abase + 512);
        async16(br0 + k0, bbase);
        async16(br1 + k0, bbase + 512);
        __syncthreads();

        bf16x8 av[4], bv[4];
#pragma unroll
        for (int i = 0; i < 4; ++i)
            av[i] = *(const bf16x8*)&As[(wr + i * 16 + l16) * 32 + sel];
#pragma unroll
        for (int j = 0; j < 4; ++j)
            bv[j] = *(const bf16x8*)&Bs[(wc + j * 16 + l16) * 32 + sel];
#pragma unroll
        for (int i = 0; i < 4; ++i)
#pragma unroll
            for (int j = 0; j < 4; ++j)
                acc[i][j] = __builtin_amdgcn_mfma_f32_16x16x32_bf16(av[i], bv[j], acc[i][j], 0, 0, 0);
        __syncthreads();
    }

    // Epilogue. C/D layout: col=lane&15, row=quad*4+reg.
    if (qm) {
        const float SC = 0.180336880f;   // 0.125 * log2(e) folded into q
#pragma unroll
        for (int j = 0; j < 4; ++j) {
            int col = n0 + wc + j * 16 + l16;
#pragma unroll
            for (int i = 0; i < 4; ++i) {
                int rowb = m0 + wr + i * 16 + quad * 4;
#pragma unroll
                for (int r = 0; r < 4; ++r)
                    q[(size_t)(rowb + r) * 1024 + col] = f2bf(acc[i][j][r] * SC);
            }
        }
        return;
    }
    int b = m0 >= 5120;
    int keyb = m0 - b * 5120;
    if (n0 < 1024) {
        // K: direct stores (32-B runs per key row)
#pragma unroll
        for (int j = 0; j < 4; ++j) {
            int col = n0 + wc + j * 16 + l16;
#pragma unroll
            for (int i = 0; i < 4; ++i) {
                int rowb = m0 + wr + i * 16 + quad * 4;
                int key = rowb - b * 5120;
                int bh = b * 16 + (col >> 6), d = col & 63;
                u16* dst = Kh + ((size_t)bh * 5120 + key) * 64 + d;
#pragma unroll
                for (int r = 0; r < 4; ++r) dst[r * 64] = f2bf(acc[i][j][r]);
            }
        }
    } else {
        // V: restage through LDS -> fully coalesced Vh[bh][d][key] writes
        u16* T = smem;   // [128][136]
#pragma unroll
        for (int j = 0; j < 4; ++j) {
            int d2 = wc + j * 16 + l16;
#pragma unroll
            for (int i = 0; i < 4; ++i) {
                int kl = wr + i * 16 + quad * 4;
                union { u16 a[4]; uint2 v; } pk;
#pragma unroll
                for (int r = 0; r < 4; ++r) pk.a[r] = f2bf(acc[i][j][r]);
                *(uint2*)&T[d2 * 136 + kl] = pk.v;
            }
        }
        __syncthreads();
        int hb = (n0 - 1024) >> 6;
#pragma unroll
        for (int p = 0; p < 8; ++p) {
            int idx = p * 256 + t;
            int d2 = idx >> 4, k0c = (idx & 15) * 8;
            uint4 vv = *(const uint4*)&T[d2 * 136 + k0c];
            int bh = b * 16 + hb + (d2 >> 6), d = d2 & 63;
            *(uint4*)(Vh + ((size_t)bh * 64 + d) * 5120 + keyb + k0c) = vv;
        }
    }
}

// ---------------------------------------------------------------------------
// Out-proj GEMM: out[2048,1024] fp32 = ao @ Wpt^T + bias. 128x64 tile.
// ---------------------------------------------------------------------------
__global__ __launch_bounds__(256, 2)
void gemm_proj(const u16* __restrict__ A, const u16* __restrict__ Bt,
               const float* __restrict__ bias, float* __restrict__ Cf)
{
    __shared__ __align__(16) u16 As[128 * 32];
    __shared__ __align__(16) u16 Bs[64 * 32];

    const int t = threadIdx.x, w = t >> 6;
    const int lane = t & 63, quad = lane >> 4, l16 = lane & 15;
    const int m0 = blockIdx.y * 128, n0 = blockIdx.x * 64;
    const int wr = w * 32;

    const int sr0 = w * 32 + (lane >> 2), sr1 = sr0 + 16;
    const int cg  = (lane & 3) ^ ((lane >> 4) & 3);
    u16* abase = As + w * 1024;
    u16* bbase = Bs + w * 512;

    const u16* ar0 = A + (size_t)(m0 + sr0) * 1024 + cg * 8;
    const u16* ar1 = A + (size_t)(m0 + sr1) * 1024 + cg * 8;
    const u16* br0 = Bt + (size_t)(n0 + w * 16 + (lane >> 2)) * 1024 + cg * 8;

    f32x4 acc[2][4] = {};
    const int sel = (quad ^ (l16 >> 2)) * 8;

    for (int k0 = 0; k0 < 1024; k0 += 32) {
        async16(ar0 + k0, abase);
        async16(ar1 + k0, abase + 512);
        async16(br0 + k0, bbase);
        __syncthreads();

        bf16x8 av[2], bv[4];
#pragma unroll
        for (int i = 0; i < 2; ++i)
            av[i] = *(const bf16x8*)&As[(wr + i * 16 + l16) * 32 + sel];
#pragma unroll
        for (int j = 0; j < 4; ++j)
            bv[j] = *(const bf16x8*)&Bs[(j * 16 + l16) * 32 + sel];
#pragma unroll
        for (int i = 0; i < 2; ++i)
#pragma unroll
            for (int j = 0; j < 4; ++j)
                acc[i][j] = __builtin_amdgcn_mfma_f32_16x16x32_bf16(av[i], bv[j], acc[i][j], 0, 0, 0);
        __syncthreads();
    }

#pragma unroll
    for (int j = 0; j < 4; ++j) {
        int col = n0 + j * 16 + l16;
        float bvl = bias[col];
#pragma unroll
        for (int i = 0; i < 2; ++i) {
            int rowb = m0 + wr + i * 16 + quad * 4;
#pragma unroll
            for (int r = 0; r < 4; ++r)
                Cf[(size_t)(rowb + r) * 1024 + col] = acc[i][j][r] + bvl;
        }
    }
}

// ---------------------------------------------------------------------------
// Split-K flash attention (R10 post-mortem: grid-tail model falsified --
// chain/lockstep-bound). THIS ROUND, attn_k only:
//  1. V fragments register-held across both rt passes (8 b128/chunk instead
//     of 16), issued right after QK to overlap exp2.
//  2. rt0/rt1 pipeline: rt1 exp2-pack under P0's LDS-write latency; P1
//     writes issued between pf0 reads and PV0 MFMAs (per-wave DS ordering
//     makes read-before-overwrite safe).
//  3. Entry stagger: co-resident blocks ((bx>>8)&3 under round-robin
//     dispatch) sleep 0/1k/2k/3k cycles -> quarter-chunk phase offsets to
//     break the 16-wave lockstep bursts.
// ---------------------------------------------------------------------------
__global__ __launch_bounds__(256, 4)
void attn_k(const u16* __restrict__ Q, const u16* __restrict__ Kh,
            const u16* __restrict__ Vh, u16* __restrict__ Op,
            float* __restrict__ Lp)
{
    __shared__ __align__(16) u16 Ks[2][4096]; // [buf][row64][slot8^(row&7)][8]
    __shared__ __align__(16) u16 Vt[2][4096]; // [buf][d64][slot8^(d&7)][8]
    __shared__ __align__(16) u16 Ps[4096];    // [wave][row16][slot8^(row&7)][8]

    const int tid  = threadIdx.x;
    const int wave = tid >> 6, lane = tid & 63;
    const int quad = lane >> 4, l16 = lane & 15;
    const int bx = blockIdx.x;
    const int x   = bx & 7;                  // XCD slot (round-robin dispatch)
    const int seq = bx >> 3;                 // 0..127 per-XCD sequence
    const int qt  = seq & 7;
    const int kg  = seq >> 3;                // 0..15
    const int g   = x + 8 * kg;              // group = (part, bh), 0..127
    const int part = g >> 5;                 // 0..3 (1280 keys each)
    const int bh   = g & 31;
    const int h = bh & 15, b = bh >> 4;

    // Phase stagger for co-resident blocks (cheap lockstep-breaker).
    {
        int ph = (bx >> 8) & 3;
        for (int i = 0; i < ph; ++i) {
            __builtin_amdgcn_s_sleep(8);
            __builtin_amdgcn_s_sleep(8);
        }
    }

    const int qrow0 = b * 1024 + qt * 128 + wave * 32;
    const u16* qbase = Q + (size_t)qrow0 * 1024 + h * 64;

    bf16x8 aq[2][2];
#pragma unroll
    for (int rt = 0; rt < 2; ++rt) {
        aq[rt][0] = *(const bf16x8*)(qbase + (size_t)(rt * 16 + l16) * 1024 +      quad * 8);
        aq[rt][1] = *(const bf16x8*)(qbase + (size_t)(rt * 16 + l16) * 1024 + 32 + quad * 8);
    }

    union { u32 u[4]; bf16x8 v; } onesf;
#pragma unroll
    for (int i = 0; i < 4; ++i) onesf.u[i] = 0x3F803F80u;

    f32x4 o[2][4] = {};
    f32x4 lacc[2] = {};

    const u16* kbase = Kh + (size_t)bh * 5120 * 64;
    const u16* vbase = Vh + (size_t)bh * 64 * 5120;
    const int l7 = l16 & 7;
    u16* psw = Ps + wave * 1024;
    const int m_beg = part * 1280;

    // Async staging geometry (per thread): LDS row r1 = tid>>3 (first half)
    // and 32+r1 (second half); phys slot sl = tid&7; logical slot sl^(r1&7).
    const int r1 = tid >> 3;
    const int sl = tid & 7;
    const int xs = sl ^ (r1 & 7);
    // K: LDS row r holds key kappa(r); kappa(r1) = 2*r1, kappa(32+r1) = 2*r1+1.
    const u16* kga = kbase + (size_t)(m_beg + 2 * r1) * 64 + xs * 8;
    // V: natural key order; row d = r1 / 32+r1.
    const u16* vga = vbase + (size_t)r1 * 5120 + m_beg + xs * 8;
    u16* kldsw = &Ks[0][0] + wave * 512;     // + lane*16B implicit
    u16* vldsw = &Vt[0][0] + wave * 512;

    // Prologue: chunk 0 into buffer 0 (latency exposed once).
    async16(kga,              kldsw);
    async16(kga + 64,         kldsw + 2048);          // key +1 (row 32+r1)
    async16(vga,              vldsw);
    async16(vga + 32 * 5120,  vldsw + 2048);          // d +32

    for (int c = 0; c < 20; ++c) {
        __syncthreads();   // drain own asyncs for chunk c; all buffers ready

        // Issue chunk c+1 into the other buffer; full compute phase hides it.
        if (c < 19) {
            const int nb = (c + 1) & 1;
            const u16* ka = kga + (size_t)(c + 1) * 4096;   // +64 keys
            const u16* va = vga + (c + 1) * 64;             // +64 keys
            u16* kd = &Ks[nb][0] + wave * 512;
            u16* vd = &Vt[nb][0] + wave * 512;
            async16(ka,             kd);
            async16(ka + 64,        kd + 2048);
            async16(va,             vd);
            async16(va + 32 * 5120, vd + 2048);
        }

        const u16* KsC = &Ks[c & 1][0];
        const u16* VtC = &Vt[c & 1][0];

        f32x4 s[2][4] = {};
        __builtin_amdgcn_s_setprio(1);
#pragma unroll
        for (int nt = 0; nt < 4; ++nt) {
            const u16* krow = KsC + (nt * 16 + l16) * 64;
            bf16x8 kb0 = *(const bf16x8*)(krow + ((quad     ^ l7) * 8));
            bf16x8 kb1 = *(const bf16x8*)(krow + (((4+quad) ^ l7) * 8));
#pragma unroll
            for (int rt = 0; rt < 2; ++rt) {
                s[rt][nt] = __builtin_amdgcn_mfma_f32_16x16x32_bf16(aq[rt][0], kb0, s[rt][nt], 0, 0, 0);
                s[rt][nt] = __builtin_amdgcn_mfma_f32_16x16x32_bf16(aq[rt][1], kb1, s[rt][nt], 0, 0, 0);
            }
        }
        __builtin_amdgcn_s_setprio(0);

        // V fragments for this chunk, shared by both rt (register-held);
        // reads overlap the exp2 blocks below.
        bf16x8 vf0[4], vf1[4];
#pragma unroll
        for (int dt = 0; dt < 4; ++dt) {
            const u16* vrow = VtC + (dt * 16 + l16) * 64;
            vf0[dt] = *(const bf16x8*)(vrow + ((quad     ^ l7) * 8));
            vf1[dt] = *(const bf16x8*)(vrow + (((4+quad) ^ l7) * 8));
        }

        // rt0 softmax -> P0 writes.
        // Lane holds keys: s[rt][0]=2*l16, s[rt][2]=2*l16+1 (pair @ word
        // l16&3, slot l16>>2), s[rt][1]/[3] = +32 (slot 4+(l16>>2)).
#pragma unroll
        for (int r = 0; r < 4; ++r) {
            float e0 = exp2f(s[0][0][r]);
            float e1 = exp2f(s[0][1][r]);
            float e2 = exp2f(s[0][2][r]);
            float e3 = exp2f(s[0][3][r]);
            u32 pwx = __builtin_amdgcn_perm(fbits(e2), fbits(e0), 0x07060302u);
            u32 pwy = __builtin_amdgcn_perm(fbits(e3), fbits(e1), 0x07060302u);
            int qr = quad * 4 + r;
            u16* prow = psw + qr * 64;
            *(u32*)(prow + ((( (l16 >> 2)    ) ^ (qr & 7)) * 8) + (l16 & 3) * 2) = pwx;
            *(u32*)(prow + ((( (l16 >> 2) + 4) ^ (qr & 7)) * 8) + (l16 & 3) * 2) = pwy;
        }

        // rt1 softmax packs overlap P0's LDS latency (kept in registers).
        u32 pw1[4][2];
#pragma unroll
        for (int r = 0; r < 4; ++r) {
            float e0 = exp2f(s[1][0][r]);
            float e1 = exp2f(s[1][1][r]);
            float e2 = exp2f(s[1][2][r]);
            float e3 = exp2f(s[1][3][r]);
            pw1[r][0] = __builtin_amdgcn_perm(fbits(e2), fbits(e0), 0x07060302u);
            pw1[r][1] = __builtin_amdgcn_perm(fbits(e3), fbits(e1), 0x07060302u);
        }

        asm volatile("s_waitcnt lgkmcnt(0)" ::: "memory");

        const u16* prow = psw + l16 * 64;
        bf16x8 pf0a = *(const bf16x8*)(prow + ((quad     ^ l7) * 8));
        bf16x8 pf0b = *(const bf16x8*)(prow + (((4+quad) ^ l7) * 8));

        // Issue P1 writes now (per-wave DS order: after pf0 reads above).
#pragma unroll
        for (int r = 0; r < 4; ++r) {
            int qr = quad * 4 + r;
            u16* prw = psw + qr * 64;
            *(u32*)(prw + ((( (l16 >> 2)    ) ^ (qr & 7)) * 8) + (l16 & 3) * 2) = pw1[r][0];
            *(u32*)(prw + ((( (l16 >> 2) + 4) ^ (qr & 7)) * 8) + (l16 & 3) * 2) = pw1[r][1];
        }

        __builtin_amdgcn_s_setprio(1);
        lacc[0] = __builtin_amdgcn_mfma_f32_16x16x32_bf16(pf0a, onesf.v, lacc[0], 0, 0, 0);
        lacc[0] = __builtin_amdgcn_mfma_f32_16x16x32_bf16(pf0b, onesf.v, lacc[0], 0, 0, 0);
#pragma unroll
        for (int dt = 0; dt < 4; ++dt) {
            o[0][dt] = __builtin_amdgcn_mfma_f32_16x16x32_bf16(pf0a, vf0[dt], o[0][dt], 0, 0, 0);
            o[0][dt] = __builtin_amdgcn_mfma_f32_16x16x32_bf16(pf0b, vf1[dt], o[0][dt], 0, 0, 0);
        }
        __builtin_amdgcn_s_setprio(0);

        asm volatile("s_waitcnt lgkmcnt(0)" ::: "memory");

        bf16x8 pf1a = *(const bf16x8*)(prow + ((quad     ^ l7) * 8));
        bf16x8 pf1b = *(const bf16x8*)(prow + (((4+quad) ^ l7) * 8));

        __builtin_amdgcn_s_setprio(1);
        lacc[1] = __builtin_amdgcn_mfma_f32_16x16x32_bf16(pf1a, onesf.v, lacc[1], 0, 0, 0);
        lacc[1] = __builtin_amdgcn_mfma_f32_16x16x32_bf16(pf1b, onesf.v, lacc[1], 0, 0, 0);
#pragma unroll
        for (int dt = 0; dt < 4; ++dt) {
            o[1][dt] = __builtin_amdgcn_mfma_f32_16x16x32_bf16(pf1a, vf0[dt], o[1][dt], 0, 0, 0);
            o[1][dt] = __builtin_amdgcn_mfma_f32_16x16x32_bf16(pf1b, vf1[dt], o[1][dt], 0, 0, 0);
        }
        __builtin_amdgcn_s_setprio(0);
        // no end barrier: next chunk writes the other Ks/Vt buffer; Ps is
        // per-wave and per-wave DS ops are in-order.
    }

    const int Rb = bh * 1024 + qt * 128 + wave * 32;
    u16* obase = Op + ((size_t)part << 21);
#pragma unroll
    for (int rt = 0; rt < 2; ++rt)
#pragma unroll
        for (int dt = 0; dt < 4; ++dt)
#pragma unroll
            for (int r = 0; r < 4; ++r) {
                int R = Rb + rt * 16 + quad * 4 + r;
                obase[(size_t)R * 64 + dt * 16 + l16] = f2bf(o[rt][dt][r]);
            }
    if (l16 == 0) {
#pragma unroll
        for (int rt = 0; rt < 2; ++rt)
#pragma unroll
            for (int r = 0; r < 4; ++r)
                Lp[part * 32768 + Rb + rt * 16 + quad * 4 + r] = lacc[rt][r];
    }
}

// ---------------------------------------------------------------------------
// Combine: ao[b,n,h*64+d] = (sum_p Op[p]) / (sum_p Lp[p]).  4 parts.
// ---------------------------------------------------------------------------
__global__ void comb_k(const u16* __restrict__ Op, const float* __restrict__ Lp,
                       u16* __restrict__ ao)
{
    int t = blockIdx.x * 256 + threadIdx.x;
    int R = t >> 4, dg = (t & 15) * 4;
    float l = Lp[R] + Lp[32768 + R] + Lp[65536 + R] + Lp[98304 + R];
    float a[4] = {0.f, 0.f, 0.f, 0.f};
#pragma unroll
    for (int p = 0; p < 4; ++p) {
        union { u16 a[4]; uint2 v; } w;
        w.v = *(const uint2*)(Op + ((size_t)p << 21) + (size_t)R * 64 + dg);
#pragma unroll
        for (int j = 0; j < 4; ++j) a[j] += bf2f(w.a[j]);
    }
    float inv = 1.f / l;
    int bh = R >> 10, n = R & 1023, b = bh >> 4, h = bh & 15;
    union { u16 a[4]; uint2 v; } out;
#pragma unroll
    for (int j = 0; j < 4; ++j) out.a[j] = f2bf(a[j] * inv);
    *(uint2*)(ao + (size_t)(b * 1024 + n) * 1024 + h * 64 + dg) = out.v;
}

// ---------------------------------------------------------------------------
// Workspace map (4 parts): Op [4,20M) fully inside dead Xc; Lp [24,24.5M)
// in dead Wkt half; Wpt [26,28M) untouched.
// ---------------------------------------------------------------------------
extern "C" void kernel_launch(void* const* d_in, const int* in_sizes, int n_in,
                              void* d_out, int out_size, void* d_ws, size_t ws_size,
                              hipStream_t stream)
{
    const float* x_obj = (const float*)d_in[0];
    const float* x_ctx = (const float*)d_in[1];
    const float* Wq    = (const float*)d_in[2];
    const float* Wkv   = (const float*)d_in[3];
    const float* Wproj = (const float*)d_in[4];
    const float* bproj = (const float*)d_in[5];
    float* out = (float*)d_out;                   // [2,1024,1024] fp32

    u16* Xc  = (u16*)d_ws;                        // [10240][1024]   20 MB
    u16* ao  = Xc;                                // alias (attn out, 4 MB)
    u16* Op  = Xc + (size_t)2097152;              // alias (partials, 16 MB)
    u16* Wqt = Xc  + (size_t)10485760;            // 2 MB
    u16* Wkt = Wqt + (size_t)1048576;             // 4 MB
    u16* Wpt = Wkt + (size_t)2097152;             // 2 MB
    u16* q   = Wpt + (size_t)1048576;             // 4 MB
    u16* Kh  = q   + (size_t)2097152;             // [32][5120][64] 20 MB
    u16* Vh  = Kh  + (size_t)10485760;            // [32][64][5120] 20 MB
    float* Lp = (float*)(Wkt + (size_t)1048576);  // [4][32768] in dead Wkt half

    dim3 blk(256);
    cvt_all_k<<<dim3(11264), blk, 0, stream>>>(x_obj, x_ctx, Xc,
                                               Wq, Wkv, Wproj, Wqt, Wkt, Wpt);
    gemm_qkv<<<dim3(1408), blk, 0, stream>>>(Xc, Wqt, Wkt, q, Kh, Vh);
    attn_k<<<dim3(1024), blk, 0, stream>>>(q, Kh, Vh, Op, Lp);
    comb_k<<<dim3(2048), blk, 0, stream>>>(Op, Lp, ao);
    gemm_proj<<<dim3(16, 16), blk, 0, stream>>>(ao, Wpt, bproj, out);
}

// Round 12
// 250.283 us; speedup vs baseline: 1.0805x; 1.0805x over previous
//
#include <hip/hip_runtime.h>
#include <stdint.h>

typedef unsigned short u16;
typedef unsigned int   u32;
typedef __attribute__((ext_vector_type(8))) short bf16x8;
typedef __attribute__((ext_vector_type(4))) float f32x4;

__device__ __forceinline__ u16 f2bf(float f) {
    union { float f; u32 u; } v; v.f = f;
    return (u16)((v.u + 0x7FFFu + ((v.u >> 16) & 1u)) >> 16);  // RNE
}
__device__ __forceinline__ float bf2f(u16 h) {
    union { u32 u; float f; } v; v.u = ((u32)h) << 16; return v.f;
}
__device__ __forceinline__ u32 fbits(float f) {
    union { float f; u32 u; } v; v.f = f; return v.u;
}

__device__ __forceinline__ void async16(const u16* g, u16* l) {
    typedef __attribute__((address_space(1))) const u32 gq;
    typedef __attribute__((address_space(3))) u32 lq;
    __builtin_amdgcn_global_load_lds((gq*)g, (lq*)l, 16, 0, 0);
}

// ---------------------------------------------------------------------------
// Prep (fused): blocks 0..10239 concat+convert x rows; 10240.. weight tiles.
// ---------------------------------------------------------------------------
__global__ void cvt_all_k(const float* __restrict__ xo, const float* __restrict__ xc,
                          u16* __restrict__ Xc,
                          const float* __restrict__ Wq, const float* __restrict__ Wkv,
                          const float* __restrict__ Wp,
                          u16* __restrict__ Wqt, u16* __restrict__ Wkt,
                          u16* __restrict__ Wpt)
{
    __shared__ __align__(16) u16 Ts[64][72];
    int id = blockIdx.x, t = threadIdx.x;
    if (id < 10240) {
        int row = id, cid = t * 4;
        int b = row >= 5120, s = row - b * 5120;
        const float* src = (s < 1024)
            ? xo + ((size_t)(b * 1024 + s)) * 1024 + cid
            : xc + ((size_t)(b * 4096 + s - 1024)) * 1024 + cid;
        float4 f = *(const float4*)src;
        union { u16 a[4]; uint2 v; } p;
        p.a[0]=f2bf(f.x); p.a[1]=f2bf(f.y); p.a[2]=f2bf(f.z); p.a[3]=f2bf(f.w);
        *(uint2*)(Xc + (size_t)row * 1024 + cid) = p.v;
        return;
    }
    int wid = id - 10240;
    const float* W; u16* Wt; int N, tile;
    if (wid < 256)      { W = Wq;  Wt = Wqt; N = 1024; tile = wid; }
    else if (wid < 768) { W = Wkv; Wt = Wkt; N = 2048; tile = wid - 256; }
    else                { W = Wp;  Wt = Wpt; N = 1024; tile = wid - 768; }
    int nt = N >> 6;
    int n0 = (tile % nt) * 64, k0 = (tile / nt) * 64;
    int lr = t >> 2, lc = (t & 3) * 16;
    const float* src = W + (size_t)(k0 + lr) * N + n0 + lc;
    union { u16 a[8]; uint4 v; } p0, p1;
    float4 f0 = *(const float4*)(src),      f1 = *(const float4*)(src + 4);
    float4 f2 = *(const float4*)(src + 8),  f3 = *(const float4*)(src + 12);
    p0.a[0]=f2bf(f0.x); p0.a[1]=f2bf(f0.y); p0.a[2]=f2bf(f0.z); p0.a[3]=f2bf(f0.w);
    p0.a[4]=f2bf(f1.x); p0.a[5]=f2bf(f1.y); p0.a[6]=f2bf(f1.z); p0.a[7]=f2bf(f1.w);
    p1.a[0]=f2bf(f2.x); p1.a[1]=f2bf(f2.y); p1.a[2]=f2bf(f2.z); p1.a[3]=f2bf(f2.w);
    p1.a[4]=f2bf(f3.x); p1.a[5]=f2bf(f3.y); p1.a[6]=f2bf(f3.z); p1.a[7]=f2bf(f3.w);
    *(uint4*)&Ts[lr][lc]     = p0.v;
    *(uint4*)&Ts[lr][lc + 8] = p1.v;
    __syncthreads();
    union { u16 a[8]; uint4 v; } q0, q1;
#pragma unroll
    for (int j = 0; j < 8; ++j) q0.a[j] = Ts[lc + j][lr];
#pragma unroll
    for (int j = 0; j < 8; ++j) q1.a[j] = Ts[lc + 8 + j][lr];
    u16* dst = Wt + (size_t)(n0 + lr) * 1024 + k0 + lc;
    *(uint4*)dst       = q0.v;
    *(uint4*)(dst + 8) = q1.v;
}

// ---------------------------------------------------------------------------
// Fused Q+KV GEMM (1408 blocks of 128x128, BK=32, m97-style).
// ---------------------------------------------------------------------------
__global__ __launch_bounds__(256, 2)
void gemm_qkv(const u16* __restrict__ A, const u16* __restrict__ Wqt,
              const u16* __restrict__ Wkt, u16* __restrict__ q,
              u16* __restrict__ Kh, u16* __restrict__ Vh)
{
    __shared__ __align__(16) u16 smem[17408];   // main: As|Bs; V-epi: T[128][136]
    u16* As = smem;
    u16* Bs = smem + 4096;

    const int t = threadIdx.x, w = t >> 6;
    const int lane = t & 63, quad = lane >> 4, l16 = lane & 15;
    const int id = blockIdx.x;
    const bool qm = id >= 1280;
    int m0, n0; const u16* Bt;
    if (qm) { int t2 = id - 1280; m0 = (t2 >> 3) * 128; n0 = (t2 & 7) * 128; Bt = Wqt; }
    else    { m0 = (id >> 4) * 128; n0 = (id & 15) * 128; Bt = Wkt; }
    const int wr = (w >> 1) * 64, wc = (w & 1) * 64;

    const int sr0 = w * 32 + (lane >> 2), sr1 = sr0 + 16;
    const int cg  = (lane & 3) ^ ((lane >> 4) & 3);
    u16* abase = As + w * 1024;
    u16* bbase = Bs + w * 1024;

    const u16 *ar0, *ar1;
    {
        int g0 = m0 + sr0, g1 = m0 + sr1;
        if (qm) {
            ar0 = A + ((size_t)(g0 >> 10) * 5120 + (g0 & 1023)) * 1024;
            ar1 = A + ((size_t)(g1 >> 10) * 5120 + (g1 & 1023)) * 1024;
        } else {
            ar0 = A + (size_t)g0 * 1024;
            ar1 = A + (size_t)g1 * 1024;
        }
        ar0 += cg * 8; ar1 += cg * 8;
    }
    const u16* br0 = Bt + (size_t)(n0 + sr0) * 1024 + cg * 8;
    const u16* br1 = Bt + (size_t)(n0 + sr1) * 1024 + cg * 8;

    f32x4 acc[4][4] = {};
    const int sel = (quad ^ (l16 >> 2)) * 8;

    for (int k0 = 0; k0 < 1024; k0 += 32) {
        async16(ar0 + k0, abase);
        async16(ar1 + k0, abase + 512);
        async16(br0 + k0, bbase);
        async16(br1 + k0, bbase + 512);
        __syncthreads();

        bf16x8 av[4], bv[4];
#pragma unroll
        for (int i = 0; i < 4; ++i)
            av[i] = *(const bf16x8*)&As[(wr + i * 16 + l16) * 32 + sel];
#pragma unroll
        for (int j = 0; j < 4; ++j)
            bv[j] = *(const bf16x8*)&Bs[(wc + j * 16 + l16) * 32 + sel];
#pragma unroll
        for (int i = 0; i < 4; ++i)
#pragma unroll
            for (int j = 0; j < 4; ++j)
                acc[i][j] = __builtin_amdgcn_mfma_f32_16x16x32_bf16(av[i], bv[j], acc[i][j], 0, 0, 0);
        __syncthreads();
    }

    // Epilogue. C/D layout: col=lane&15, row=quad*4+reg.
    if (qm) {
        const float SC = 0.180336880f;   // 0.125 * log2(e) folded into q
#pragma unroll
        for (int j = 0; j < 4; ++j) {
            int col = n0 + wc + j * 16 + l16;
#pragma unroll
            for (int i = 0; i < 4; ++i) {
                int rowb = m0 + wr + i * 16 + quad * 4;
#pragma unroll
                for (int r = 0; r < 4; ++r)
                    q[(size_t)(rowb + r) * 1024 + col] = f2bf(acc[i][j][r] * SC);
            }
        }
        return;
    }
    int b = m0 >= 5120;
    int keyb = m0 - b * 5120;
    if (n0 < 1024) {
        // K: direct stores (32-B runs per key row)
#pragma unroll
        for (int j = 0; j < 4; ++j) {
            int col = n0 + wc + j * 16 + l16;
#pragma unroll
            for (int i = 0; i < 4; ++i) {
                int rowb = m0 + wr + i * 16 + quad * 4;
                int key = rowb - b * 5120;
                int bh = b * 16 + (col >> 6), d = col & 63;
                u16* dst = Kh + ((size_t)bh * 5120 + key) * 64 + d;
#pragma unroll
                for (int r = 0; r < 4; ++r) dst[r * 64] = f2bf(acc[i][j][r]);
            }
        }
    } else {
        // V: restage through LDS -> fully coalesced Vh[bh][d][key] writes
        u16* T = smem;   // [128][136]
#pragma unroll
        for (int j = 0; j < 4; ++j) {
            int d2 = wc + j * 16 + l16;
#pragma unroll
            for (int i = 0; i < 4; ++i) {
                int kl = wr + i * 16 + quad * 4;
                union { u16 a[4]; uint2 v; } pk;
#pragma unroll
                for (int r = 0; r < 4; ++r) pk.a[r] = f2bf(acc[i][j][r]);
                *(uint2*)&T[d2 * 136 + kl] = pk.v;
            }
        }
        __syncthreads();
        int hb = (n0 - 1024) >> 6;
#pragma unroll
        for (int p = 0; p < 8; ++p) {
            int idx = p * 256 + t;
            int d2 = idx >> 4, k0c = (idx & 15) * 8;
            uint4 vv = *(const uint4*)&T[d2 * 136 + k0c];
            int bh = b * 16 + hb + (d2 >> 6), d = d2 & 63;
            *(uint4*)(Vh + ((size_t)bh * 64 + d) * 5120 + keyb + k0c) = vv;
        }
    }
}

// ---------------------------------------------------------------------------
// Out-proj GEMM: out[2048,1024] fp32 = ao @ Wpt^T + bias. 128x64 tile.
// ---------------------------------------------------------------------------
__global__ __launch_bounds__(256, 2)
void gemm_proj(const u16* __restrict__ A, const u16* __restrict__ Bt,
               const float* __restrict__ bias, float* __restrict__ Cf)
{
    __shared__ __align__(16) u16 As[128 * 32];
    __shared__ __align__(16) u16 Bs[64 * 32];

    const int t = threadIdx.x, w = t >> 6;
    const int lane = t & 63, quad = lane >> 4, l16 = lane & 15;
    const int m0 = blockIdx.y * 128, n0 = blockIdx.x * 64;
    const int wr = w * 32;

    const int sr0 = w * 32 + (lane >> 2), sr1 = sr0 + 16;
    const int cg  = (lane & 3) ^ ((lane >> 4) & 3);
    u16* abase = As + w * 1024;
    u16* bbase = Bs + w * 512;

    const u16* ar0 = A + (size_t)(m0 + sr0) * 1024 + cg * 8;
    const u16* ar1 = A + (size_t)(m0 + sr1) * 1024 + cg * 8;
    const u16* br0 = Bt + (size_t)(n0 + w * 16 + (lane >> 2)) * 1024 + cg * 8;

    f32x4 acc[2][4] = {};
    const int sel = (quad ^ (l16 >> 2)) * 8;

    for (int k0 = 0; k0 < 1024; k0 += 32) {
        async16(ar0 + k0, abase);
        async16(ar1 + k0, abase + 512);
        async16(br0 + k0, bbase);
        __syncthreads();

        bf16x8 av[2], bv[4];
#pragma unroll
        for (int i = 0; i < 2; ++i)
            av[i] = *(const bf16x8*)&As[(wr + i * 16 + l16) * 32 + sel];
#pragma unroll
        for (int j = 0; j < 4; ++j)
            bv[j] = *(const bf16x8*)&Bs[(j * 16 + l16) * 32 + sel];
#pragma unroll
        for (int i = 0; i < 2; ++i)
#pragma unroll
            for (int j = 0; j < 4; ++j)
                acc[i][j] = __builtin_amdgcn_mfma_f32_16x16x32_bf16(av[i], bv[j], acc[i][j], 0, 0, 0);
        __syncthreads();
    }

#pragma unroll
    for (int j = 0; j < 4; ++j) {
        int col = n0 + j * 16 + l16;
        float bvl = bias[col];
#pragma unroll
        for (int i = 0; i < 2; ++i) {
            int rowb = m0 + wr + i * 16 + quad * 4;
#pragma unroll
            for (int r = 0; r < 4; ++r)
                Cf[(size_t)(rowb + r) * 1024 + col] = acc[i][j][r] + bvl;
        }
    }
}

// ---------------------------------------------------------------------------
// Split-K flash attention (R11 post-mortem: register-held V = +64 VGPR ->
// scratch spill, WRITE 90 MB, -20 us. Revert to R10 and keep ONLY the
// register-neutral rt pipeline):
//  * rt1 exp2+pack BEFORE the first lgkmcnt(0): s[1] (16 regs) dies into
//    pw1 (8 regs) -- net -8 pressure; fills P0's LDS-write latency.
//  * P1 writes issued between pf0 reads and PV0 MFMAs (per-wave DS order
//    makes read-before-overwrite safe) -> second lgkmcnt wait covered by
//    10 MFMAs + write issue.
//  * V read from LDS per rt pass exactly as R10. No stagger.
// ---------------------------------------------------------------------------
__global__ __launch_bounds__(256, 4)
void attn_k(const u16* __restrict__ Q, const u16* __restrict__ Kh,
            const u16* __restrict__ Vh, u16* __restrict__ Op,
            float* __restrict__ Lp)
{
    __shared__ __align__(16) u16 Ks[2][4096]; // [buf][row64][slot8^(row&7)][8]
    __shared__ __align__(16) u16 Vt[2][4096]; // [buf][d64][slot8^(d&7)][8]
    __shared__ __align__(16) u16 Ps[4096];    // [wave][row16][slot8^(row&7)][8]

    const int tid  = threadIdx.x;
    const int wave = tid >> 6, lane = tid & 63;
    const int quad = lane >> 4, l16 = lane & 15;
    const int bx = blockIdx.x;
    const int x   = bx & 7;                  // XCD slot (round-robin dispatch)
    const int seq = bx >> 3;                 // 0..127 per-XCD sequence
    const int qt  = seq & 7;
    const int kg  = seq >> 3;                // 0..15
    const int g   = x + 8 * kg;              // group = (part, bh), 0..127
    const int part = g >> 5;                 // 0..3 (1280 keys each)
    const int bh   = g & 31;
    const int h = bh & 15, b = bh >> 4;

    const int qrow0 = b * 1024 + qt * 128 + wave * 32;
    const u16* qbase = Q + (size_t)qrow0 * 1024 + h * 64;

    bf16x8 aq[2][2];
#pragma unroll
    for (int rt = 0; rt < 2; ++rt) {
        aq[rt][0] = *(const bf16x8*)(qbase + (size_t)(rt * 16 + l16) * 1024 +      quad * 8);
        aq[rt][1] = *(const bf16x8*)(qbase + (size_t)(rt * 16 + l16) * 1024 + 32 + quad * 8);
    }

    union { u32 u[4]; bf16x8 v; } onesf;
#pragma unroll
    for (int i = 0; i < 4; ++i) onesf.u[i] = 0x3F803F80u;

    f32x4 o[2][4] = {};
    f32x4 lacc[2] = {};

    const u16* kbase = Kh + (size_t)bh * 5120 * 64;
    const u16* vbase = Vh + (size_t)bh * 64 * 5120;
    const int l7 = l16 & 7;
    u16* psw = Ps + wave * 1024;
    const int m_beg = part * 1280;

    // Async staging geometry (per thread): LDS row r1 = tid>>3 (first half)
    // and 32+r1 (second half); phys slot sl = tid&7; logical slot sl^(r1&7).
    const int r1 = tid >> 3;
    const int sl = tid & 7;
    const int xs = sl ^ (r1 & 7);
    // K: LDS row r holds key kappa(r); kappa(r1) = 2*r1, kappa(32+r1) = 2*r1+1.
    const u16* kga = kbase + (size_t)(m_beg + 2 * r1) * 64 + xs * 8;
    // V: natural key order; row d = r1 / 32+r1.
    const u16* vga = vbase + (size_t)r1 * 5120 + m_beg + xs * 8;
    u16* kldsw = &Ks[0][0] + wave * 512;     // + lane*16B implicit
    u16* vldsw = &Vt[0][0] + wave * 512;

    // Prologue: chunk 0 into buffer 0 (latency exposed once).
    async16(kga,              kldsw);
    async16(kga + 64,         kldsw + 2048);          // key +1 (row 32+r1)
    async16(vga,              vldsw);
    async16(vga + 32 * 5120,  vldsw + 2048);          // d +32

    for (int c = 0; c < 20; ++c) {
        __syncthreads();   // drain own asyncs for chunk c; all buffers ready

        // Issue chunk c+1 into the other buffer; full compute phase hides it.
        if (c < 19) {
            const int nb = (c + 1) & 1;
            const u16* ka = kga + (size_t)(c + 1) * 4096;   // +64 keys
            const u16* va = vga + (c + 1) * 64;             // +64 keys
            u16* kd = &Ks[nb][0] + wave * 512;
            u16* vd = &Vt[nb][0] + wave * 512;
            async16(ka,             kd);
            async16(ka + 64,        kd + 2048);
            async16(va,             vd);
            async16(va + 32 * 5120, vd + 2048);
        }

        const u16* KsC = &Ks[c & 1][0];
        const u16* VtC = &Vt[c & 1][0];

        f32x4 s[2][4] = {};
        __builtin_amdgcn_s_setprio(1);
#pragma unroll
        for (int nt = 0; nt < 4; ++nt) {
            const u16* krow = KsC + (nt * 16 + l16) * 64;
            bf16x8 kb0 = *(const bf16x8*)(krow + ((quad     ^ l7) * 8));
            bf16x8 kb1 = *(const bf16x8*)(krow + (((4+quad) ^ l7) * 8));
#pragma unroll
            for (int rt = 0; rt < 2; ++rt) {
                s[rt][nt] = __builtin_amdgcn_mfma_f32_16x16x32_bf16(aq[rt][0], kb0, s[rt][nt], 0, 0, 0);
                s[rt][nt] = __builtin_amdgcn_mfma_f32_16x16x32_bf16(aq[rt][1], kb1, s[rt][nt], 0, 0, 0);
            }
        }
        __builtin_amdgcn_s_setprio(0);

        // rt0 softmax -> P0 writes.
        // Lane holds keys: s[rt][0]=2*l16, s[rt][2]=2*l16+1 (pair @ word
        // l16&3, slot l16>>2), s[rt][1]/[3] = +32 (slot 4+(l16>>2)).
#pragma unroll
        for (int r = 0; r < 4; ++r) {
            float e0 = exp2f(s[0][0][r]);
            float e1 = exp2f(s[0][1][r]);
            float e2 = exp2f(s[0][2][r]);
            float e3 = exp2f(s[0][3][r]);
            u32 pwx = __builtin_amdgcn_perm(fbits(e2), fbits(e0), 0x07060302u);
            u32 pwy = __builtin_amdgcn_perm(fbits(e3), fbits(e1), 0x07060302u);
            int qr = quad * 4 + r;
            u16* prow = psw + qr * 64;
            *(u32*)(prow + ((( (l16 >> 2)    ) ^ (qr & 7)) * 8) + (l16 & 3) * 2) = pwx;
            *(u32*)(prow + ((( (l16 >> 2) + 4) ^ (qr & 7)) * 8) + (l16 & 3) * 2) = pwy;
        }

        // rt1 softmax packs overlap P0's LDS-write latency (registers only;
        // s[1] dies into pw1 -> net register pressure DECREASES).
        u32 pw1[4][2];
#pragma unroll
        for (int r = 0; r < 4; ++r) {
            float e0 = exp2f(s[1][0][r]);
            float e1 = exp2f(s[1][1][r]);
            float e2 = exp2f(s[1][2][r]);
            float e3 = exp2f(s[1][3][r]);
            pw1[r][0] = __builtin_amdgcn_perm(fbits(e2), fbits(e0), 0x07060302u);
            pw1[r][1] = __builtin_amdgcn_perm(fbits(e3), fbits(e1), 0x07060302u);
        }

        asm volatile("s_waitcnt lgkmcnt(0)" ::: "memory");

        const u16* prow = psw + l16 * 64;
        bf16x8 pf0a = *(const bf16x8*)(prow + ((quad     ^ l7) * 8));
        bf16x8 pf0b = *(const bf16x8*)(prow + (((4+quad) ^ l7) * 8));

        // Issue P1 writes now (per-wave DS order: after pf0 reads above).
#pragma unroll
        for (int r = 0; r < 4; ++r) {
            int qr = quad * 4 + r;
            u16* prw = psw + qr * 64;
            *(u32*)(prw + ((( (l16 >> 2)    ) ^ (qr & 7)) * 8) + (l16 & 3) * 2) = pw1[r][0];
            *(u32*)(prw + ((( (l16 >> 2) + 4) ^ (qr & 7)) * 8) + (l16 & 3) * 2) = pw1[r][1];
        }

        __builtin_amdgcn_s_setprio(1);
        lacc[0] = __builtin_amdgcn_mfma_f32_16x16x32_bf16(pf0a, onesf.v, lacc[0], 0, 0, 0);
        lacc[0] = __builtin_amdgcn_mfma_f32_16x16x32_bf16(pf0b, onesf.v, lacc[0], 0, 0, 0);
#pragma unroll
        for (int dt = 0; dt < 4; ++dt) {
            const u16* vrow = VtC + (dt * 16 + l16) * 64;
            bf16x8 v0 = *(const bf16x8*)(vrow + ((quad     ^ l7) * 8));
            bf16x8 v1 = *(const bf16x8*)(vrow + (((4+quad) ^ l7) * 8));
            o[0][dt] = __builtin_amdgcn_mfma_f32_16x16x32_bf16(pf0a, v0, o[0][dt], 0, 0, 0);
            o[0][dt] = __builtin_amdgcn_mfma_f32_16x16x32_bf16(pf0b, v1, o[0][dt], 0, 0, 0);
        }
        __builtin_amdgcn_s_setprio(0);

        asm volatile("s_waitcnt lgkmcnt(0)" ::: "memory");

        bf16x8 pf1a = *(const bf16x8*)(prow + ((quad     ^ l7) * 8));
        bf16x8 pf1b = *(const bf16x8*)(prow + (((4+quad) ^ l7) * 8));

        __builtin_amdgcn_s_setprio(1);
        lacc[1] = __builtin_amdgcn_mfma_f32_16x16x32_bf16(pf1a, onesf.v, lacc[1], 0, 0, 0);
        lacc[1] = __builtin_amdgcn_mfma_f32_16x16x32_bf16(pf1b, onesf.v, lacc[1], 0, 0, 0);
#pragma unroll
        for (int dt = 0; dt < 4; ++dt) {
            const u16* vrow = VtC + (dt * 16 + l16) * 64;
            bf16x8 v0 = *(const bf16x8*)(vrow + ((quad     ^ l7) * 8));
            bf16x8 v1 = *(const bf16x8*)(vrow + (((4+quad) ^ l7) * 8));
            o[1][dt] = __builtin_amdgcn_mfma_f32_16x16x32_bf16(pf1a, v0, o[1][dt], 0, 0, 0);
            o[1][dt] = __builtin_amdgcn_mfma_f32_16x16x32_bf16(pf1b, v1, o[1][dt], 0, 0, 0);
        }
        __builtin_amdgcn_s_setprio(0);
        // no end barrier: next chunk writes the other Ks/Vt buffer; Ps is
        // per-wave and per-wave DS ops are in-order.
    }

    const int Rb = bh * 1024 + qt * 128 + wave * 32;
    u16* obase = Op + ((size_t)part << 21);
#pragma unroll
    for (int rt = 0; rt < 2; ++rt)
#pragma unroll
        for (int dt = 0; dt < 4; ++dt)
#pragma unroll
            for (int r = 0; r < 4; ++r) {
                int R = Rb + rt * 16 + quad * 4 + r;
                obase[(size_t)R * 64 + dt * 16 + l16] = f2bf(o[rt][dt][r]);
            }
    if (l16 == 0) {
#pragma unroll
        for (int rt = 0; rt < 2; ++rt)
#pragma unroll
            for (int r = 0; r < 4; ++r)
                Lp[part * 32768 + Rb + rt * 16 + quad * 4 + r] = lacc[rt][r];
    }
}

// ---------------------------------------------------------------------------
// Combine: ao[b,n,h*64+d] = (sum_p Op[p]) / (sum_p Lp[p]).  4 parts.
// ---------------------------------------------------------------------------
__global__ void comb_k(const u16* __restrict__ Op, const float* __restrict__ Lp,
                       u16* __restrict__ ao)
{
    int t = blockIdx.x * 256 + threadIdx.x;
    int R = t >> 4, dg = (t & 15) * 4;
    float l = Lp[R] + Lp[32768 + R] + Lp[65536 + R] + Lp[98304 + R];
    float a[4] = {0.f, 0.f, 0.f, 0.f};
#pragma unroll
    for (int p = 0; p < 4; ++p) {
        union { u16 a[4]; uint2 v; } w;
        w.v = *(const uint2*)(Op + ((size_t)p << 21) + (size_t)R * 64 + dg);
#pragma unroll
        for (int j = 0; j < 4; ++j) a[j] += bf2f(w.a[j]);
    }
    float inv = 1.f / l;
    int bh = R >> 10, n = R & 1023, b = bh >> 4, h = bh & 15;
    union { u16 a[4]; uint2 v; } out;
#pragma unroll
    for (int j = 0; j < 4; ++j) out.a[j] = f2bf(a[j] * inv);
    *(uint2*)(ao + (size_t)(b * 1024 + n) * 1024 + h * 64 + dg) = out.v;
}

// ---------------------------------------------------------------------------
// Workspace map (4 parts): Op [4,20M) fully inside dead Xc; Lp [24,24.5M)
// in dead Wkt half; Wpt [26,28M) untouched.
// ---------------------------------------------------------------------------
extern "C" void kernel_launch(void* const* d_in, const int* in_sizes, int n_in,
                              void* d_out, int out_size, void* d_ws, size_t ws_size,
                              hipStream_t stream)
{
    const float* x_obj = (const float*)d_in[0];
    const float* x_ctx = (const float*)d_in[1];
    const float* Wq    = (const float*)d_in[2];
    const float* Wkv   = (const float*)d_in[3];
    const float* Wproj = (const float*)d_in[4];
    const float* bproj = (const float*)d_in[5];
    float* out = (float*)d_out;                   // [2,1024,1024] fp32

    u16* Xc  = (u16*)d_ws;                        // [10240][1024]   20 MB
    u16* ao  = Xc;                                // alias (attn out, 4 MB)
    u16* Op  = Xc + (size_t)2097152;              // alias (partials, 16 MB)
    u16* Wqt = Xc  + (size_t)10485760;            // 2 MB
    u16* Wkt = Wqt + (size_t)1048576;             // 4 MB
    u16* Wpt = Wkt + (size_t)2097152;             // 2 MB
    u16* q   = Wpt + (size_t)1048576;             // 4 MB
    u16* Kh  = q   + (size_t)2097152;             // [32][5120][64] 20 MB
    u16* Vh  = Kh  + (size_t)10485760;            // [32][64][5120] 20 MB
    float* Lp = (float*)(Wkt + (size_t)1048576);  // [4][32768] in dead Wkt half

    dim3 blk(256);
    cvt_all_k<<<dim3(11264), blk, 0, stream>>>(x_obj, x_ctx, Xc,
                                               Wq, Wkv, Wproj, Wqt, Wkt, Wpt);
    gemm_qkv<<<dim3(1408), blk, 0, stream>>>(Xc, Wqt, Wkt, q, Kh, Vh);
    attn_k<<<dim3(1024), blk, 0, stream>>>(q, Kh, Vh, Op, Lp);
    comb_k<<<dim3(2048), blk, 0, stream>>>(Op, Lp, ao);
    gemm_proj<<<dim3(16, 16), blk, 0, stream>>>(ao, Wpt, bproj, out);
}

// Round 13
// 247.306 us; speedup vs baseline: 1.0935x; 1.0120x over previous
//
#include <hip/hip_runtime.h>
#include <stdint.h>

typedef unsigned short u16;
typedef unsigned int   u32;
typedef __attribute__((ext_vector_type(8))) short bf16x8;
typedef __attribute__((ext_vector_type(4))) float f32x4;

__device__ __forceinline__ u16 f2bf(float f) {
    union { float f; u32 u; } v; v.f = f;
    return (u16)((v.u + 0x7FFFu + ((v.u >> 16) & 1u)) >> 16);  // RNE
}
__device__ __forceinline__ float bf2f(u16 h) {
    union { u32 u; float f; } v; v.u = ((u32)h) << 16; return v.f;
}
__device__ __forceinline__ u32 fbits(float f) {
    union { float f; u32 u; } v; v.f = f; return v.u;
}

__device__ __forceinline__ void async16(const u16* g, u16* l) {
    typedef __attribute__((address_space(1))) const u32 gq;
    typedef __attribute__((address_space(3))) u32 lq;
    __builtin_amdgcn_global_load_lds((gq*)g, (lq*)l, 16, 0, 0);
}

// ---------------------------------------------------------------------------
// Prep (fused): blocks 0..10239 concat+convert x rows; 10240.. weight tiles.
// ---------------------------------------------------------------------------
__global__ void cvt_all_k(const float* __restrict__ xo, const float* __restrict__ xc,
                          u16* __restrict__ Xc,
                          const float* __restrict__ Wq, const float* __restrict__ Wkv,
                          const float* __restrict__ Wp,
                          u16* __restrict__ Wqt, u16* __restrict__ Wkt,
                          u16* __restrict__ Wpt)
{
    __shared__ __align__(16) u16 Ts[64][72];
    int id = blockIdx.x, t = threadIdx.x;
    if (id < 10240) {
        int row = id, cid = t * 4;
        int b = row >= 5120, s = row - b * 5120;
        const float* src = (s < 1024)
            ? xo + ((size_t)(b * 1024 + s)) * 1024 + cid
            : xc + ((size_t)(b * 4096 + s - 1024)) * 1024 + cid;
        float4 f = *(const float4*)src;
        union { u16 a[4]; uint2 v; } p;
        p.a[0]=f2bf(f.x); p.a[1]=f2bf(f.y); p.a[2]=f2bf(f.z); p.a[3]=f2bf(f.w);
        *(uint2*)(Xc + (size_t)row * 1024 + cid) = p.v;
        return;
    }
    int wid = id - 10240;
    const float* W; u16* Wt; int N, tile;
    if (wid < 256)      { W = Wq;  Wt = Wqt; N = 1024; tile = wid; }
    else if (wid < 768) { W = Wkv; Wt = Wkt; N = 2048; tile = wid - 256; }
    else                { W = Wp;  Wt = Wpt; N = 1024; tile = wid - 768; }
    int nt = N >> 6;
    int n0 = (tile % nt) * 64, k0 = (tile / nt) * 64;
    int lr = t >> 2, lc = (t & 3) * 16;
    const float* src = W + (size_t)(k0 + lr) * N + n0 + lc;
    union { u16 a[8]; uint4 v; } p0, p1;
    float4 f0 = *(const float4*)(src),      f1 = *(const float4*)(src + 4);
    float4 f2 = *(const float4*)(src + 8),  f3 = *(const float4*)(src + 12);
    p0.a[0]=f2bf(f0.x); p0.a[1]=f2bf(f0.y); p0.a[2]=f2bf(f0.z); p0.a[3]=f2bf(f0.w);
    p0.a[4]=f2bf(f1.x); p0.a[5]=f2bf(f1.y); p0.a[6]=f2bf(f1.z); p0.a[7]=f2bf(f1.w);
    p1.a[0]=f2bf(f2.x); p1.a[1]=f2bf(f2.y); p1.a[2]=f2bf(f2.z); p1.a[3]=f2bf(f2.w);
    p1.a[4]=f2bf(f3.x); p1.a[5]=f2bf(f3.y); p1.a[6]=f2bf(f3.z); p1.a[7]=f2bf(f3.w);
    *(uint4*)&Ts[lr][lc]     = p0.v;
    *(uint4*)&Ts[lr][lc + 8] = p1.v;
    __syncthreads();
    union { u16 a[8]; uint4 v; } q0, q1;
#pragma unroll
    for (int j = 0; j < 8; ++j) q0.a[j] = Ts[lc + j][lr];
#pragma unroll
    for (int j = 0; j < 8; ++j) q1.a[j] = Ts[lc + 8 + j][lr];
    u16* dst = Wt + (size_t)(n0 + lr) * 1024 + k0 + lc;
    *(uint4*)dst       = q0.v;
    *(uint4*)(dst + 8) = q1.v;
}

// ---------------------------------------------------------------------------
// Fused Q+KV GEMM (1408 blocks of 128x128, BK=32, m97-style).
// ---------------------------------------------------------------------------
__global__ __launch_bounds__(256, 2)
void gemm_qkv(const u16* __restrict__ A, const u16* __restrict__ Wqt,
              const u16* __restrict__ Wkt, u16* __restrict__ q,
              u16* __restrict__ Kh, u16* __restrict__ Vh)
{
    __shared__ __align__(16) u16 smem[17408];   // main: As|Bs; V-epi: T[128][136]
    u16* As = smem;
    u16* Bs = smem + 4096;

    const int t = threadIdx.x, w = t >> 6;
    const int lane = t & 63, quad = lane >> 4, l16 = lane & 15;
    const int id = blockIdx.x;
    const bool qm = id >= 1280;
    int m0, n0; const u16* Bt;
    if (qm) { int t2 = id - 1280; m0 = (t2 >> 3) * 128; n0 = (t2 & 7) * 128; Bt = Wqt; }
    else    { m0 = (id >> 4) * 128; n0 = (id & 15) * 128; Bt = Wkt; }
    const int wr = (w >> 1) * 64, wc = (w & 1) * 64;

    const int sr0 = w * 32 + (lane >> 2), sr1 = sr0 + 16;
    const int cg  = (lane & 3) ^ ((lane >> 4) & 3);
    u16* abase = As + w * 1024;
    u16* bbase = Bs + w * 1024;

    const u16 *ar0, *ar1;
    {
        int g0 = m0 + sr0, g1 = m0 + sr1;
        if (qm) {
            ar0 = A + ((size_t)(g0 >> 10) * 5120 + (g0 & 1023)) * 1024;
            ar1 = A + ((size_t)(g1 >> 10) * 5120 + (g1 & 1023)) * 1024;
        } else {
            ar0 = A + (size_t)g0 * 1024;
            ar1 = A + (size_t)g1 * 1024;
        }
        ar0 += cg * 8; ar1 += cg * 8;
    }
    const u16* br0 = Bt + (size_t)(n0 + sr0) * 1024 + cg * 8;
    const u16* br1 = Bt + (size_t)(n0 + sr1) * 1024 + cg * 8;

    f32x4 acc[4][4] = {};
    const int sel = (quad ^ (l16 >> 2)) * 8;

    for (int k0 = 0; k0 < 1024; k0 += 32) {
        async16(ar0 + k0, abase);
        async16(ar1 + k0, abase + 512);
        async16(br0 + k0, bbase);
        async16(br1 + k0, bbase + 512);
        __syncthreads();

        bf16x8 av[4], bv[4];
#pragma unroll
        for (int i = 0; i < 4; ++i)
            av[i] = *(const bf16x8*)&As[(wr + i * 16 + l16) * 32 + sel];
#pragma unroll
        for (int j = 0; j < 4; ++j)
            bv[j] = *(const bf16x8*)&Bs[(wc + j * 16 + l16) * 32 + sel];
#pragma unroll
        for (int i = 0; i < 4; ++i)
#pragma unroll
            for (int j = 0; j < 4; ++j)
                acc[i][j] = __builtin_amdgcn_mfma_f32_16x16x32_bf16(av[i], bv[j], acc[i][j], 0, 0, 0);
        __syncthreads();
    }

    // Epilogue. C/D layout: col=lane&15, row=quad*4+reg.
    if (qm) {
        const float SC = 0.180336880f;   // 0.125 * log2(e) folded into q
#pragma unroll
        for (int j = 0; j < 4; ++j) {
            int col = n0 + wc + j * 16 + l16;
#pragma unroll
            for (int i = 0; i < 4; ++i) {
                int rowb = m0 + wr + i * 16 + quad * 4;
#pragma unroll
                for (int r = 0; r < 4; ++r)
                    q[(size_t)(rowb + r) * 1024 + col] = f2bf(acc[i][j][r] * SC);
            }
        }
        return;
    }
    int b = m0 >= 5120;
    int keyb = m0 - b * 5120;
    if (n0 < 1024) {
        // K: direct stores (32-B runs per key row)
#pragma unroll
        for (int j = 0; j < 4; ++j) {
            int col = n0 + wc + j * 16 + l16;
#pragma unroll
            for (int i = 0; i < 4; ++i) {
                int rowb = m0 + wr + i * 16 + quad * 4;
                int key = rowb - b * 5120;
                int bh = b * 16 + (col >> 6), d = col & 63;
                u16* dst = Kh + ((size_t)bh * 5120 + key) * 64 + d;
#pragma unroll
                for (int r = 0; r < 4; ++r) dst[r * 64] = f2bf(acc[i][j][r]);
            }
        }
    } else {
        // V: restage through LDS -> fully coalesced Vh[bh][d][key] writes
        u16* T = smem;   // [128][136]
#pragma unroll
        for (int j = 0; j < 4; ++j) {
            int d2 = wc + j * 16 + l16;
#pragma unroll
            for (int i = 0; i < 4; ++i) {
                int kl = wr + i * 16 + quad * 4;
                union { u16 a[4]; uint2 v; } pk;
#pragma unroll
                for (int r = 0; r < 4; ++r) pk.a[r] = f2bf(acc[i][j][r]);
                *(uint2*)&T[d2 * 136 + kl] = pk.v;
            }
        }
        __syncthreads();
        int hb = (n0 - 1024) >> 6;
#pragma unroll
        for (int p = 0; p < 8; ++p) {
            int idx = p * 256 + t;
            int d2 = idx >> 4, k0c = (idx & 15) * 8;
            uint4 vv = *(const uint4*)&T[d2 * 136 + k0c];
            int bh = b * 16 + hb + (d2 >> 6), d = d2 & 63;
            *(uint4*)(Vh + ((size_t)bh * 64 + d) * 5120 + keyb + k0c) = vv;
        }
    }
}

// ---------------------------------------------------------------------------
// Out-proj GEMM: out[2048,1024] fp32 = ao @ Wpt^T + bias. 128x64 tile.
// ---------------------------------------------------------------------------
__global__ __launch_bounds__(256, 2)
void gemm_proj(const u16* __restrict__ A, const u16* __restrict__ Bt,
               const float* __restrict__ bias, float* __restrict__ Cf)
{
    __shared__ __align__(16) u16 As[128 * 32];
    __shared__ __align__(16) u16 Bs[64 * 32];

    const int t = threadIdx.x, w = t >> 6;
    const int lane = t & 63, quad = lane >> 4, l16 = lane & 15;
    const int m0 = blockIdx.y * 128, n0 = blockIdx.x * 64;
    const int wr = w * 32;

    const int sr0 = w * 32 + (lane >> 2), sr1 = sr0 + 16;
    const int cg  = (lane & 3) ^ ((lane >> 4) & 3);
    u16* abase = As + w * 1024;
    u16* bbase = Bs + w * 512;

    const u16* ar0 = A + (size_t)(m0 + sr0) * 1024 + cg * 8;
    const u16* ar1 = A + (size_t)(m0 + sr1) * 1024 + cg * 8;
    const u16* br0 = Bt + (size_t)(n0 + w * 16 + (lane >> 2)) * 1024 + cg * 8;

    f32x4 acc[2][4] = {};
    const int sel = (quad ^ (l16 >> 2)) * 8;

    for (int k0 = 0; k0 < 1024; k0 += 32) {
        async16(ar0 + k0, abase);
        async16(ar1 + k0, abase + 512);
        async16(br0 + k0, bbase);
        __syncthreads();

        bf16x8 av[2], bv[4];
#pragma unroll
        for (int i = 0; i < 2; ++i)
            av[i] = *(const bf16x8*)&As[(wr + i * 16 + l16) * 32 + sel];
#pragma unroll
        for (int j = 0; j < 4; ++j)
            bv[j] = *(const bf16x8*)&Bs[(j * 16 + l16) * 32 + sel];
#pragma unroll
        for (int i = 0; i < 2; ++i)
#pragma unroll
            for (int j = 0; j < 4; ++j)
                acc[i][j] = __builtin_amdgcn_mfma_f32_16x16x32_bf16(av[i], bv[j], acc[i][j], 0, 0, 0);
        __syncthreads();
    }

#pragma unroll
    for (int j = 0; j < 4; ++j) {
        int col = n0 + j * 16 + l16;
        float bvl = bias[col];
#pragma unroll
        for (int i = 0; i < 2; ++i) {
            int rowb = m0 + wr + i * 16 + quad * 4;
#pragma unroll
            for (int r = 0; r < 4; ++r)
                Cf[(size_t)(rowb + r) * 1024 + col] = acc[i][j][r] + bvl;
        }
    }
}

// ---------------------------------------------------------------------------
// Split-K flash attention, SWAPPED-QK / in-register-P variant.
// Key insight: 16x16x32 A-frag (row=l16, k=quad*8+j) and B-frag
// (k=quad*8+j, col=l16) have IDENTICAL per-lane shapes -> mfma(kb, aq)
// computes S^T with zero data movement changes: lane holds q-row l16,
// keys 16nt+quad*4+r. P then packs straight into the PV A-operand in
// REGISTERS -- the P-through-LDS round trip (16 stores + 2 lgkmcnt waits
// + 4 reads per chunk, the R12 critical path) is deleted, as is Ps (LDS
// 40->32 KB).
//  * K: natural key order (R9 interleave obsolete), async DMA as before.
//  * V: key-permuted LDS rows so B-frag keys match pa's:
//    kappa(g*8+j) = [g<4: 16*(j>>2)+g*4 | g>=4: 32+16*(j>>2)+(g-4)*4] + (j&3)
//    -> two 4-key runs per 16B group -> reg-staged (4x8B loads prefetched a
//    full chunk ahead, 2 ds_write_b128 at iter top; T14 pattern, +8 VGPR).
//  * V LDS reads once per dt, shared by both rt (16 -> 8 b128/chunk).
//  * PV/lacc output mapping unchanged (col=l16=d, row=quad*4+r=q) ->
//    epilogue identical. Register peak ~110 < 128 cap (WRITE = spill
//    tripwire per R3/R11).
// ---------------------------------------------------------------------------
__global__ __launch_bounds__(256, 4)
void attn_k(const u16* __restrict__ Q, const u16* __restrict__ Kh,
            const u16* __restrict__ Vh, u16* __restrict__ Op,
            float* __restrict__ Lp)
{
    __shared__ __align__(16) u16 Ks[2][4096]; // [buf][key64][slot8^(key&7)][8]
    __shared__ __align__(16) u16 Vt[2][4096]; // [buf][d64][slot8^(d&7)][8], key-permuted

    const int tid  = threadIdx.x;
    const int wave = tid >> 6, lane = tid & 63;
    const int quad = lane >> 4, l16 = lane & 15;
    const int bx = blockIdx.x;
    const int x   = bx & 7;                  // XCD slot (round-robin dispatch)
    const int seq = bx >> 3;                 // 0..127 per-XCD sequence
    const int qt  = seq & 7;
    const int kg  = seq >> 3;                // 0..15
    const int g   = x + 8 * kg;              // group = (part, bh), 0..127
    const int part = g >> 5;                 // 0..3 (1280 keys each)
    const int bh   = g & 31;
    const int h = bh & 15, b = bh >> 4;

    const int qrow0 = b * 1024 + qt * 128 + wave * 32;
    const u16* qbase = Q + (size_t)qrow0 * 1024 + h * 64;

    bf16x8 aq[2][2];
#pragma unroll
    for (int rt = 0; rt < 2; ++rt) {
        aq[rt][0] = *(const bf16x8*)(qbase + (size_t)(rt * 16 + l16) * 1024 +      quad * 8);
        aq[rt][1] = *(const bf16x8*)(qbase + (size_t)(rt * 16 + l16) * 1024 + 32 + quad * 8);
    }

    union { u32 u[4]; bf16x8 v; } onesf;
#pragma unroll
    for (int i = 0; i < 4; ++i) onesf.u[i] = 0x3F803F80u;

    f32x4 o[2][4] = {};
    f32x4 lacc[2] = {};

    const u16* kbase = Kh + (size_t)bh * 5120 * 64;
    const u16* vbase = Vh + (size_t)bh * 64 * 5120;
    const int l7 = l16 & 7;
    const int m_beg = part * 1280;

    // Staging geometry: thread covers rows r1 and 32+r1; phys slot sl;
    // logical slot/group xs = sl ^ (r1&7) (same for row 32+r1).
    const int r1 = tid >> 3;
    const int sl = tid & 7;
    const int xs = sl ^ (r1 & 7);
    // K natural order: row r = key r.
    const u16* kga = kbase + (size_t)(m_beg + r1) * 64 + xs * 8;
    u16* kldsw = &Ks[0][0] + wave * 512;     // + lane*16B implicit
    // V permuted: logical group xs covers keys koff..koff+3 and koff+16..+19
    // (koff = xs*4 for xs<4, 32+(xs-4)*4 for xs>=4).
    const int koff = (xs < 4) ? (xs * 4) : (32 + (xs - 4) * 4);
    const u16* vga0 = vbase + (size_t)r1 * 5120 + m_beg + koff;        // row d=r1
    const u16* vga1 = vga0 + (size_t)32 * 5120;                        // row d=32+r1
    u16* vd0 = (u16*)0; // per-buffer dest computed in loop
    const int vdoff0 = r1 * 64 + sl * 8;            // phys addr of row r1, slot sl
    const int vdoff1 = (32 + r1) * 64 + sl * 8;

    // Prologue: chunk 0 K async into buf0; V loads into regs.
    async16(kga,        kldsw);
    async16(kga + 2048, kldsw + 2048);               // keys +32
    uint2 va0 = *(const uint2*)(vga0);
    uint2 va1 = *(const uint2*)(vga0 + 16);
    uint2 vb0 = *(const uint2*)(vga1);
    uint2 vb1 = *(const uint2*)(vga1 + 16);

    for (int c = 0; c < 20; ++c) {
        // Write staged V(c) to buf c&1 (last read two barriers ago; safe).
        {
            u16* vbuf = &Vt[c & 1][0];
            uint4 w0; w0.x = va0.x; w0.y = va0.y; w0.z = va1.x; w0.w = va1.y;
            uint4 w1; w1.x = vb0.x; w1.y = vb0.y; w1.z = vb1.x; w1.w = vb1.y;
            *(uint4*)(vbuf + vdoff0) = w0;
            *(uint4*)(vbuf + vdoff1) = w1;
        }
        __syncthreads();   // drains own K asyncs (vmcnt) + V ds_writes (lgkm)

        // Prefetch chunk c+1: K async into other buf; V global loads to regs.
        if (c < 19) {
            const u16* ka = kga + (size_t)(c + 1) * 4096;
            u16* kd = &Ks[(c + 1) & 1][0] + wave * 512;
            async16(ka,        kd);
            async16(ka + 2048, kd + 2048);
            const u16* vp0 = vga0 + (c + 1) * 64;
            const u16* vp1 = vga1 + (c + 1) * 64;
            va0 = *(const uint2*)(vp0);
            va1 = *(const uint2*)(vp0 + 16);
            vb0 = *(const uint2*)(vp1);
            vb1 = *(const uint2*)(vp1 + 16);
        }

        const u16* KsC = &Ks[c & 1][0];
        const u16* VtC = &Vt[c & 1][0];

        // Swapped QK: s[rt][nt] = S^T tile -> lane: q=l16, keys 16nt+quad*4+r.
        f32x4 s[2][4] = {};
        __builtin_amdgcn_s_setprio(1);
#pragma unroll
        for (int nt = 0; nt < 4; ++nt) {
            const u16* krow = KsC + (nt * 16 + l16) * 64;
            bf16x8 kb0 = *(const bf16x8*)(krow + ((quad     ^ l7) * 8));
            bf16x8 kb1 = *(const bf16x8*)(krow + (((4+quad) ^ l7) * 8));
#pragma unroll
            for (int rt = 0; rt < 2; ++rt) {
                s[rt][nt] = __builtin_amdgcn_mfma_f32_16x16x32_bf16(kb0, aq[rt][0], s[rt][nt], 0, 0, 0);
                s[rt][nt] = __builtin_amdgcn_mfma_f32_16x16x32_bf16(kb1, aq[rt][1], s[rt][nt], 0, 0, 0);
            }
        }
        __builtin_amdgcn_s_setprio(0);

        // In-register softmax -> PV A-operand. pa[rt][half] elem j holds
        // P[q=l16][kappa(quad*8+j)]; pairs (2m,2m+1) = (nt=2*half+(m>>1),
        // r=2(m&1)) and r+1 -> u32 = perm(odd, even).
        union { u32 u[4]; bf16x8 v; } pa[2][2];
#pragma unroll
        for (int rt = 0; rt < 2; ++rt)
#pragma unroll
            for (int hf = 0; hf < 2; ++hf)
#pragma unroll
                for (int m = 0; m < 4; ++m) {
                    int nt = 2 * hf + (m >> 1);
                    int re = 2 * (m & 1);
                    float ee = exp2f(s[rt][nt][re]);
                    float eo = exp2f(s[rt][nt][re + 1]);
                    pa[rt][hf].u[m] = __builtin_amdgcn_perm(fbits(eo), fbits(ee), 0x07060302u);
                }

        __builtin_amdgcn_s_setprio(1);
#pragma unroll
        for (int rt = 0; rt < 2; ++rt) {
            lacc[rt] = __builtin_amdgcn_mfma_f32_16x16x32_bf16(pa[rt][0].v, onesf.v, lacc[rt], 0, 0, 0);
            lacc[rt] = __builtin_amdgcn_mfma_f32_16x16x32_bf16(pa[rt][1].v, onesf.v, lacc[rt], 0, 0, 0);
        }
#pragma unroll
        for (int dt = 0; dt < 4; ++dt) {
            const u16* vrow = VtC + (dt * 16 + l16) * 64;
            bf16x8 v0 = *(const bf16x8*)(vrow + ((quad     ^ l7) * 8));
            bf16x8 v1 = *(const bf16x8*)(vrow + (((4+quad) ^ l7) * 8));
#pragma unroll
            for (int rt = 0; rt < 2; ++rt) {
                o[rt][dt] = __builtin_amdgcn_mfma_f32_16x16x32_bf16(pa[rt][0].v, v0, o[rt][dt], 0, 0, 0);
                o[rt][dt] = __builtin_amdgcn_mfma_f32_16x16x32_bf16(pa[rt][1].v, v1, o[rt][dt], 0, 0, 0);
            }
        }
        __builtin_amdgcn_s_setprio(0);
        // no end barrier: next chunk writes the other Ks/Vt buffer.
    }

    const int Rb = bh * 1024 + qt * 128 + wave * 32;
    u16* obase = Op + ((size_t)part << 21);
#pragma unroll
    for (int rt = 0; rt < 2; ++rt)
#pragma unroll
        for (int dt = 0; dt < 4; ++dt)
#pragma unroll
            for (int r = 0; r < 4; ++r) {
                int R = Rb + rt * 16 + quad * 4 + r;
                obase[(size_t)R * 64 + dt * 16 + l16] = f2bf(o[rt][dt][r]);
            }
    if (l16 == 0) {
#pragma unroll
        for (int rt = 0; rt < 2; ++rt)
#pragma unroll
            for (int r = 0; r < 4; ++r)
                Lp[part * 32768 + Rb + rt * 16 + quad * 4 + r] = lacc[rt][r];
    }
}

// ---------------------------------------------------------------------------
// Combine: ao[b,n,h*64+d] = (sum_p Op[p]) / (sum_p Lp[p]).  4 parts.
// ---------------------------------------------------------------------------
__global__ void comb_k(const u16* __restrict__ Op, const float* __restrict__ Lp,
                       u16* __restrict__ ao)
{
    int t = blockIdx.x * 256 + threadIdx.x;
    int R = t >> 4, dg = (t & 15) * 4;
    float l = Lp[R] + Lp[32768 + R] + Lp[65536 + R] + Lp[98304 + R];
    float a[4] = {0.f, 0.f, 0.f, 0.f};
#pragma unroll
    for (int p = 0; p < 4; ++p) {
        union { u16 a[4]; uint2 v; } w;
        w.v = *(const uint2*)(Op + ((size_t)p << 21) + (size_t)R * 64 + dg);
#pragma unroll
        for (int j = 0; j < 4; ++j) a[j] += bf2f(w.a[j]);
    }
    float inv = 1.f / l;
    int bh = R >> 10, n = R & 1023, b = bh >> 4, h = bh & 15;
    union { u16 a[4]; uint2 v; } out;
#pragma unroll
    for (int j = 0; j < 4; ++j) out.a[j] = f2bf(a[j] * inv);
    *(uint2*)(ao + (size_t)(b * 1024 + n) * 1024 + h * 64 + dg) = out.v;
}

// ---------------------------------------------------------------------------
// Workspace map (4 parts): Op [4,20M) fully inside dead Xc; Lp [24,24.5M)
// in dead Wkt half; Wpt [26,28M) untouched.
// ---------------------------------------------------------------------------
extern "C" void kernel_launch(void* const* d_in, const int* in_sizes, int n_in,
                              void* d_out, int out_size, void* d_ws, size_t ws_size,
                              hipStream_t stream)
{
    const float* x_obj = (const float*)d_in[0];
    const float* x_ctx = (const float*)d_in[1];
    const float* Wq    = (const float*)d_in[2];
    const float* Wkv   = (const float*)d_in[3];
    const float* Wproj = (const float*)d_in[4];
    const float* bproj = (const float*)d_in[5];
    float* out = (float*)d_out;                   // [2,1024,1024] fp32

    u16* Xc  = (u16*)d_ws;                        // [10240][1024]   20 MB
    u16* ao  = Xc;                                // alias (attn out, 4 MB)
    u16* Op  = Xc + (size_t)2097152;              // alias (partials, 16 MB)
    u16* Wqt = Xc  + (size_t)10485760;            // 2 MB
    u16* Wkt = Wqt + (size_t)1048576;             // 4 MB
    u16* Wpt = Wkt + (size_t)2097152;             // 2 MB
    u16* q   = Wpt + (size_t)1048576;             // 4 MB
    u16* Kh  = q   + (size_t)2097152;             // [32][5120][64] 20 MB
    u16* Vh  = Kh  + (size_t)10485760;            // [32][64][5120] 20 MB
    float* Lp = (float*)(Wkt + (size_t)1048576);  // [4][32768] in dead Wkt half

    dim3 blk(256);
    cvt_all_k<<<dim3(11264), blk, 0, stream>>>(x_obj, x_ctx, Xc,
                                               Wq, Wkv, Wproj, Wqt, Wkt, Wpt);
    gemm_qkv<<<dim3(1408), blk, 0, stream>>>(Xc, Wqt, Wkt, q, Kh, Vh);
    attn_k<<<dim3(1024), blk, 0, stream>>>(q, Kh, Vh, Op, Lp);
    comb_k<<<dim3(2048), blk, 0, stream>>>(Op, Lp, ao);
    gemm_proj<<<dim3(16, 16), blk, 0, stream>>>(ao, Wpt, bproj, out);
}